// Round 3
// baseline (1625.153 us; speedup 1.0000x reference)
//
#include <hip/hip_runtime.h>
#include <hip/hip_bf16.h>
#include <cstdint>

// Shapes (compile-time constants for this problem)
#define B_    2
#define T_    1024
#define NT_   30
#define H_    1024
#define L_    8
#define F_    2816
#define NH_   16
#define R_    16
#define HD_   64
#define M_    2048          // B*T
#define NTP1_ 31

typedef unsigned short u16;
typedef short  s16x8 __attribute__((ext_vector_type(8)));   // MFMA bf16 operand
typedef unsigned short u16x4 __attribute__((ext_vector_type(4)));
typedef unsigned short u16x8 __attribute__((ext_vector_type(8)));
typedef float  f32x4 __attribute__((ext_vector_type(4)));

__device__ __forceinline__ u16 f2bf(float f){
  __hip_bfloat16 h = __float2bfloat16(f);
  return __builtin_bit_cast(unsigned short, h);
}
__device__ __forceinline__ float bf2f(u16 u){
  uint32_t v = (uint32_t)u << 16;
  return __builtin_bit_cast(float, v);
}

__device__ __forceinline__ void async16(const void* g, void* l){
  __builtin_amdgcn_global_load_lds((const __attribute__((address_space(1))) void*)g,
                                   (__attribute__((address_space(3))) void*)l, 16, 0, 0);
}

// ---------------------------------------------------------------------------
// Unified prep: fold all 4 LoRA weight groups (bf16, transposed) + embed,
// one dispatch.  Wt[n][k] = W[k][n] + 2 * sum_r A[r][k] * Bm[n][r]
// block map: [0,6144) qkv fold, [6144,8192) o fold, [8192,19456) gu fold,
// [19456,25088) d fold, [25088,27136) embed rows.
// ---------------------------------------------------------------------------
struct FoldSmem {
  float Wt_s[64][65];   // [n][k]
  float As[16][64];     // [r][k]
  float Bs[64][20];     // [n][r]
};

__device__ __forceinline__ void fold_tile(
    const float* __restrict__ W, const float* __restrict__ A,
    const float* __restrict__ Bm, u16* __restrict__ Wt,
    int K, int N, int k0, int n0, FoldSmem& sm)
{
  const int tid = threadIdx.x;
  {
    const int kr = tid >> 4;
    const int n4 = (tid & 15) * 4;
    #pragma unroll
    for (int p = 0; p < 4; p++){
      int krow = p * 16 + kr;
      float4 w = *(const float4*)(W + (long)(k0 + krow) * N + n0 + n4);
      sm.Wt_s[n4+0][krow] = w.x; sm.Wt_s[n4+1][krow] = w.y;
      sm.Wt_s[n4+2][krow] = w.z; sm.Wt_s[n4+3][krow] = w.w;
    }
    const int r = tid >> 4, kc = (tid & 15) * 4;
    *(float4*)&sm.As[r][kc] = *(const float4*)(A + (long)r * K + k0 + kc);
    const int nb = tid >> 2, r4 = (tid & 3) * 4;
    float4 b = *(const float4*)(Bm + (long)(n0 + nb) * 16 + r4);
    sm.Bs[nb][r4+0]=b.x; sm.Bs[nb][r4+1]=b.y; sm.Bs[nb][r4+2]=b.z; sm.Bs[nb][r4+3]=b.w;
  }
  __syncthreads();
  const int ko = (tid & 7) * 8;
  const int na = tid >> 3;
  float bq0[16], bq1[16];
  #pragma unroll
  for (int c = 0; c < 4; c++){
    *(float4*)&bq0[c*4] = *(const float4*)&sm.Bs[na][c*4];
    *(float4*)&bq1[c*4] = *(const float4*)&sm.Bs[na+32][c*4];
  }
  float l0[8] = {}, l1[8] = {};
  #pragma unroll
  for (int r = 0; r < 16; r++){
    float a[8];
    *(float4*)&a[0] = *(const float4*)&sm.As[r][ko];
    *(float4*)&a[4] = *(const float4*)&sm.As[r][ko+4];
    #pragma unroll
    for (int j = 0; j < 8; j++){
      l0[j] += a[j] * bq0[r];
      l1[j] += a[j] * bq1[r];
    }
  }
  u16x8 o0, o1;
  #pragma unroll
  for (int j = 0; j < 8; j++){
    o0[j] = f2bf(sm.Wt_s[na][ko+j]    + 2.0f * l0[j]);
    o1[j] = f2bf(sm.Wt_s[na+32][ko+j] + 2.0f * l1[j]);
  }
  *(u16x8*)(Wt + (long)(n0+na)*K    + k0 + ko) = o0;
  *(u16x8*)(Wt + (long)(n0+na+32)*K + k0 + ko) = o1;
}

__global__ __launch_bounds__(256, 4) void prep_kernel(
    const float* __restrict__ Wqkv, const float* __restrict__ Aqkv,
    const float* __restrict__ Bqkv, u16* __restrict__ wt_qkv,
    const float* __restrict__ Wo, const float* __restrict__ Ao,
    const float* __restrict__ Bo, u16* __restrict__ wt_o,
    const float* __restrict__ Wgu, const float* __restrict__ Agu,
    const float* __restrict__ Bgu, u16* __restrict__ wt_gu,
    const float* __restrict__ Wd, const float* __restrict__ Ad,
    const float* __restrict__ Bd, u16* __restrict__ wt_d,
    const float* __restrict__ x, const float* __restrict__ sw,
    const float* __restrict__ sb, float* __restrict__ h)
{
  __shared__ FoldSmem sm;
  const int id = blockIdx.x;
  if (id < 25088){
    const float *W, *A, *Bm; u16* Wt; int K, N, k0, n0;
    if (id < 6144){               // qkv: 24 mats x (16k x 16n)
      int z = id >> 8, r = id & 255;
      W = Wqkv + (long)z * 1048576; A = Aqkv + (long)z * 16384;
      Bm = Bqkv + (long)z * 16384; Wt = wt_qkv + (long)z * 1048576;
      K = 1024; N = 1024; k0 = (r & 15) * 64; n0 = (r >> 4) * 64;
    } else if (id < 8192){        // o: 8 mats x (16k x 16n)
      int t = id - 6144; int z = t >> 8, r = t & 255;
      W = Wo + (long)z * 1048576; A = Ao + (long)z * 16384;
      Bm = Bo + (long)z * 16384;  Wt = wt_o + (long)z * 1048576;
      K = 1024; N = 1024; k0 = (r & 15) * 64; n0 = (r >> 4) * 64;
    } else if (id < 19456){       // gu: 16 mats x (16k x 44n)
      int t = id - 8192; int z = t / 704, r = t % 704;
      W = Wgu + (long)z * 2883584; A = Agu + (long)z * 16384;
      Bm = Bgu + (long)z * 45056;  Wt = wt_gu + (long)z * 2883584;
      K = 1024; N = 2816; k0 = (r % 16) * 64; n0 = (r / 16) * 64;
    } else {                      // d: 8 mats x (44k x 16n)
      int t = id - 19456; int z = t / 704, r = t % 704;
      W = Wd + (long)z * 2883584; A = Ad + (long)z * 45056;
      Bm = Bd + (long)z * 16384;  Wt = wt_d + (long)z * 2883584;
      K = 2816; N = 1024; k0 = (r % 44) * 64; n0 = (r / 44) * 64;
    }
    fold_tile(W, A, Bm, Wt, K, N, k0, n0, sm);
  } else {                        // embed rows
    const int m = id - 25088;
    const float* xr = x + (long)m * NT_;
    for (int jj = threadIdx.x; jj < H_; jj += 256){
      float acc = sb[jj];
      #pragma unroll
      for (int i = 0; i < NT_; i++) acc += xr[i] * sw[i * H_ + jj];
      h[(long)m * H_ + jj] = acc;
    }
  }
}

// ---------------------------------------------------------------------------
// RMSNorm rows -> bf16, optionally fusing h += sum of nparts bf16 split-K
// partials (pb strided M_*H_), writing h back. grid M_/4, 256 thr, 4 rows/blk.
// ---------------------------------------------------------------------------
__global__ __launch_bounds__(256) void rms_kernel(
    float* __restrict__ hsrc, const u16* __restrict__ pb,
    const float* __restrict__ w, u16* __restrict__ outp, int nparts)
{
  const int t = threadIdx.x;
  __shared__ float red[4];
  const float4 wv = ((const float4*)w)[t];
  for (int it = 0; it < 4; it++){
    const int m = blockIdx.x * 4 + it;
    float4 v = ((const float4*)(hsrc + (long)m * H_))[t];
    if (nparts){
      for (int k = 0; k < nparts; k++){
        u16x4 a = *(const u16x4*)(pb + (long)k * M_ * H_ + (long)m * H_ + t * 4);
        v.x += bf2f(a[0]); v.y += bf2f(a[1]); v.z += bf2f(a[2]); v.w += bf2f(a[3]);
      }
      ((float4*)(hsrc + (long)m * H_))[t] = v;
    }
    float ss = v.x*v.x + v.y*v.y + v.z*v.z + v.w*v.w;
    #pragma unroll
    for (int off = 32; off >= 1; off >>= 1) ss += __shfl_xor(ss, off);
    if ((t & 63) == 0) red[t >> 6] = ss;
    __syncthreads();
    const float scale = rsqrtf((red[0]+red[1]+red[2]+red[3]) * (1.0f/H_) + 1e-6f);
    u16x4 o;
    o[0] = f2bf(v.x*scale*wv.x); o[1] = f2bf(v.y*scale*wv.y);
    o[2] = f2bf(v.z*scale*wv.z); o[3] = f2bf(v.w*scale*wv.w);
    *(u16x4*)(outp + (long)m * H_ + t * 4) = o;
    __syncthreads();
  }
}

// ---------------------------------------------------------------------------
// GEMM: C[m][n] = A(M,K)bf16 @ Bt(N,K)bf16^T.  OUTBF=1 -> bf16 out, 0 -> fp32.
// m97 structure: BK=64, 2-barrier K-loop, global_load_lds width-16 staging.
// Split-K over gridDim.z. grid (M/128, N/128, Z), 256 thr, 3 blocks/CU.
// ---------------------------------------------------------------------------
template<int OUTBF>
__global__ __launch_bounds__(256, 3) void gemm_bt(
    const u16* __restrict__ Ag, const u16* __restrict__ Btg, void* __restrict__ Cptr,
    int Ndim, int Kstride, int Ksteps, long zsC)
{
  const int z = blockIdx.z, Z = (int)gridDim.z;
  const int kb = Ksteps / Z, rem = Ksteps % Z;
  const int sblk = (z < rem) ? z * (kb + 1) : rem * (kb + 1) + (z - rem) * kb;
  const int klen = (kb + (z < rem ? 1 : 0)) * 64;
  Ag  += (long)sblk * 64;
  Btg += (long)sblk * 64;
  const int m0 = blockIdx.x * 128, n0 = blockIdx.y * 128;
  __shared__ alignas(16) u16 As[128 * 64];
  __shared__ alignas(16) u16 Bs[128 * 64];
  const int tid = threadIdx.x;
  const int wave = tid >> 6, lane = tid & 63;
  const int wm = (wave & 1) * 64, wn = (wave >> 1) * 64;
  const int fr = lane & 15, quad = lane >> 4;

  f32x4 acc[4][4] = {};

  for (int kt = 0; kt < klen; kt += 64){
    __syncthreads();
    #pragma unroll
    for (int c = 0; c < 4; c++){
      int lin = c * 256 + tid;
      int row = lin >> 3, p = lin & 7;
      int gc = ((p ^ (row & 7)) * 8);
      async16(Ag  + (long)(m0 + row) * Kstride + kt + gc, As + lin * 8);
      async16(Btg + (long)(n0 + row) * Kstride + kt + gc, Bs + lin * 8);
    }
    __syncthreads();
    #pragma unroll
    for (int kk = 0; kk < 2; kk++){
      s16x8 af[4], bg[4];
      #pragma unroll
      for (int i = 0; i < 4; i++){
        int rA = wm + i * 16 + fr;
        af[i] = *(const s16x8*)(As + rA * 64 + (((kk*4 + quad) ^ (rA & 7)) * 8));
        int rB = wn + i * 16 + fr;
        bg[i] = *(const s16x8*)(Bs + rB * 64 + (((kk*4 + quad) ^ (rB & 7)) * 8));
      }
      #pragma unroll
      for (int i = 0; i < 4; i++)
        #pragma unroll
        for (int j = 0; j < 4; j++)
          acc[i][j] = __builtin_amdgcn_mfma_f32_16x16x32_bf16(af[i], bg[j], acc[i][j], 0, 0, 0);
    }
  }
  #pragma unroll
  for (int i = 0; i < 4; i++){
    int row0 = m0 + wm + i * 16 + quad * 4;
    #pragma unroll
    for (int j = 0; j < 4; j++){
      int col = n0 + wn + j * 16 + fr;
      #pragma unroll
      for (int r = 0; r < 4; r++){
        long idx = (long)(row0 + r) * Ndim + col;
        if (OUTBF){
          u16* C = (u16*)Cptr + (long)blockIdx.z * zsC;
          C[idx] = f2bf(acc[i][j][r]);
        } else {
          float* C = (float*)Cptr + (long)blockIdx.z * zsC;
          C[idx] = acc[i][j][r];
        }
      }
    }
  }
}

// ---------------------------------------------------------------------------
// qkv GEMM with fused RoPE (q,k) + V-transpose epilogue.
// A = hn (M,1024) bf16, Bt = wt_qkv (3072,1024) bf16 n-major.
// grid (16, 24): by 0..7 -> q, 8..15 -> k, 16..23 -> v (uniform per block).
// ---------------------------------------------------------------------------
__global__ __launch_bounds__(256, 3) void gemm_qkv(
    const u16* __restrict__ Ag, const u16* __restrict__ Btg,
    u16* __restrict__ qr, u16* __restrict__ kr, u16* __restrict__ vt)
{
  const int m0 = blockIdx.x * 128, n0 = blockIdx.y * 128;
  __shared__ alignas(16) u16 As[128 * 64];
  __shared__ alignas(16) u16 Bs[128 * 64];
  const int tid = threadIdx.x;
  const int wave = tid >> 6, lane = tid & 63;
  const int wm = (wave & 1) * 64, wn = (wave >> 1) * 64;
  const int fr = lane & 15, quad = lane >> 4;

  f32x4 acc[4][4] = {};

  for (int kt = 0; kt < H_; kt += 64){
    __syncthreads();
    #pragma unroll
    for (int c = 0; c < 4; c++){
      int lin = c * 256 + tid;
      int row = lin >> 3, p = lin & 7;
      int gc = ((p ^ (row & 7)) * 8);
      async16(Ag  + (long)(m0 + row) * H_ + kt + gc, As + lin * 8);
      async16(Btg + (long)(n0 + row) * H_ + kt + gc, Bs + lin * 8);
    }
    __syncthreads();
    #pragma unroll
    for (int kk = 0; kk < 2; kk++){
      s16x8 af[4], bg[4];
      #pragma unroll
      for (int i = 0; i < 4; i++){
        int rA = wm + i * 16 + fr;
        af[i] = *(const s16x8*)(As + rA * 64 + (((kk*4 + quad) ^ (rA & 7)) * 8));
        int rB = wn + i * 16 + fr;
        bg[i] = *(const s16x8*)(Bs + rB * 64 + (((kk*4 + quad) ^ (rB & 7)) * 8));
      }
      #pragma unroll
      for (int i = 0; i < 4; i++)
        #pragma unroll
        for (int j = 0; j < 4; j++)
          acc[i][j] = __builtin_amdgcn_mfma_f32_16x16x32_bf16(af[i], bg[j], acc[i][j], 0, 0, 0);
    }
  }
  const int sel  = n0 >> 10;               // 0=q 1=k 2=v
  const int nloc = (n0 & 1023) + wn;       // within-matrix col base of this wave
  const int hh   = nloc >> 6;              // head index (wave-uniform)
  if (sel == 2){
    #pragma unroll
    for (int i = 0; i < 4; i++){
      int row0 = m0 + wm + i * 16 + quad * 4;
      int b = row0 >> 10, t0 = row0 & 1023;
      #pragma unroll
      for (int j = 0; j < 4; j++){
        int d = j * 16 + fr;
        u16x4 o;
        #pragma unroll
        for (int r = 0; r < 4; r++) o[r] = f2bf(acc[i][j][r]);
        *(u16x4*)(vt + ((long)((b * NH_ + hh) * HD_ + d)) * T_ + t0) = o;
      }
    }
  } else {
    u16* dst = sel ? kr : qr;
    #pragma unroll
    for (int i = 0; i < 4; i++){
      int row0 = m0 + wm + i * 16 + quad * 4;
      int b = row0 >> 10;
      #pragma unroll
      for (int j = 0; j < 2; j++){
        int d1 = j * 16 + fr;                    // 0..31
        float freq = exp2f((float)d1 * (-13.287712379549449f / 32.0f)); // 10000^(-d1/32)
        #pragma unroll
        for (int r = 0; r < 4; r++){
          int t = (row0 + r) & 1023;
          float x1 = acc[i][j][r], x2 = acc[i][j + 2][r];
          float sn, cs; __sincosf((float)t * freq, &sn, &cs);
          long base = ((long)(b * NH_ + hh) * T_ + t) * HD_;
          dst[base + d1]      = f2bf(x1 * cs - x2 * sn);
          dst[base + d1 + 32] = f2bf(x2 * cs + x1 * sn);
        }
      }
    }
  }
}

// ---------------------------------------------------------------------------
// Fused gate/up GEMM + SiLU, 128x64 tile: act[m][n] = silu(A@Wg^T)*(A@Wu^T).
// grid (M/128, F/64), 256 thr, 3 blocks/CU.
// ---------------------------------------------------------------------------
__global__ __launch_bounds__(256, 3) void gemm_gu(
    const u16* __restrict__ Ag, const u16* __restrict__ Bgw,
    const u16* __restrict__ Buw, u16* __restrict__ actb)
{
  const int m0 = blockIdx.x * 128, n0 = blockIdx.y * 64;
  __shared__ alignas(16) u16 As[128 * 64];
  __shared__ alignas(16) u16 Bg_[64 * 64];
  __shared__ alignas(16) u16 Bu_[64 * 64];
  const int tid = threadIdx.x;
  const int wave = tid >> 6, lane = tid & 63;
  const int wm = (wave & 1) * 64, wn = (wave >> 1) * 32;
  const int fr = lane & 15, quad = lane >> 4;

  f32x4 accg[4][2] = {}, accu[4][2] = {};

  for (int kt = 0; kt < H_; kt += 64){
    __syncthreads();
    #pragma unroll
    for (int c = 0; c < 4; c++){
      int lin = c * 256 + tid;
      int row = lin >> 3, p = lin & 7;
      async16(Ag + (long)(m0 + row) * H_ + kt + ((p ^ (row & 7)) * 8), As + lin * 8);
    }
    #pragma unroll
    for (int c = 0; c < 2; c++){
      int lin = c * 256 + tid;
      int row = lin >> 3, p = lin & 7;
      int gc = ((p ^ (row & 7)) * 8);
      async16(Bgw + (long)(n0 + row) * H_ + kt + gc, Bg_ + lin * 8);
      async16(Buw + (long)(n0 + row) * H_ + kt + gc, Bu_ + lin * 8);
    }
    __syncthreads();
    #pragma unroll
    for (int kk = 0; kk < 2; kk++){
      s16x8 af[4], bg[2], bu[2];
      #pragma unroll
      for (int i = 0; i < 4; i++){
        int rA = wm + i * 16 + fr;
        af[i] = *(const s16x8*)(As + rA * 64 + (((kk*4 + quad) ^ (rA & 7)) * 8));
      }
      #pragma unroll
      for (int j = 0; j < 2; j++){
        int rB = wn + j * 16 + fr;
        bg[j] = *(const s16x8*)(Bg_ + rB * 64 + (((kk*4 + quad) ^ (rB & 7)) * 8));
        bu[j] = *(const s16x8*)(Bu_ + rB * 64 + (((kk*4 + quad) ^ (rB & 7)) * 8));
      }
      #pragma unroll
      for (int i = 0; i < 4; i++)
        #pragma unroll
        for (int j = 0; j < 2; j++){
          accg[i][j] = __builtin_amdgcn_mfma_f32_16x16x32_bf16(af[i], bg[j], accg[i][j], 0, 0, 0);
          accu[i][j] = __builtin_amdgcn_mfma_f32_16x16x32_bf16(af[i], bu[j], accu[i][j], 0, 0, 0);
        }
    }
  }
  #pragma unroll
  for (int i = 0; i < 4; i++){
    int row0 = m0 + wm + i * 16 + quad * 4;
    #pragma unroll
    for (int j = 0; j < 2; j++){
      int col = n0 + wn + j * 16 + fr;
      #pragma unroll
      for (int r = 0; r < 4; r++){
        float g = accg[i][j][r], u = accu[i][j][r];
        float act = g / (1.0f + __expf(-g)) * u;
        actb[(long)(row0 + r) * F_ + col] = f2bf(act);
      }
    }
  }
}

// ---------------------------------------------------------------------------
// Flash attention: grid (16, B_*NH_), 256 thr. One q-tile per block.
// Q and V are read directly from global (L2-hot, no in-block reuse for Q,
// cross-wave-only reuse for V -> staging was overhead; m169 precedent).
// Only K stays LDS-staged (4x cross-wave reuse). LDS 33.4KB -> 3 blocks/CU.
// qt reversed for b=1 so CU pairs (id, id+256) get qt and 15-qt: balanced.
// ---------------------------------------------------------------------------
__global__ __launch_bounds__(256, 3) void attn_kernel(
    const u16* __restrict__ qr, const u16* __restrict__ kr,
    const u16* __restrict__ vt, u16* __restrict__ att)
{
  const int bh = blockIdx.y;
  const int b = bh >> 4, hh = bh & 15;
  const int qt = b ? (15 - (int)blockIdx.x) : (int)blockIdx.x;
  __shared__ alignas(16) u16 Ks[128 * 64];
  __shared__ alignas(16) u16 Ps[64 * 136];
  const int tid = threadIdx.x;
  const int wave = tid >> 6, lane = tid & 63, fr = lane & 15, quad = lane >> 4;
  const int wrow = wave * 16;
  const u16* kgb = kr + (long)bh * T_ * HD_;
  const u16* vgb = vt + (long)bh * HD_ * T_;
  const u16* qg  = qr + ((long)bh * T_ + qt * 64) * HD_;

  // Q fragments straight from global (row wrow+fr, col chunk (kk*4+quad)*8)
  s16x8 aq[2];
  #pragma unroll
  for (int kk = 0; kk < 2; kk++)
    aq[kk] = *(const s16x8*)(qg + (wrow + fr) * HD_ + kk * 32 + quad * 8);

  f32x4 o_acc[4] = {};
  float m_r[4] = {-1e30f, -1e30f, -1e30f, -1e30f};
  float l_r[4] = {};
  const int kmax = (qt * 64 + 63) >> 7;

  for (int kt = 0; kt <= kmax; kt++){
    __syncthreads();
    const u16* kg = kgb + (long)kt * 128 * HD_;
    #pragma unroll
    for (int c = 0; c < 4; c++){
      int lin = c * 256 + tid, row = lin >> 3, p = lin & 7;
      async16(kg + row * HD_ + ((p ^ (row & 7)) * 8), Ks + lin * 8);
    }
    __syncthreads();

    f32x4 s[8] = {};
    __builtin_amdgcn_s_setprio(1);
    #pragma unroll
    for (int ik = 0; ik < 8; ik++){
      #pragma unroll
      for (int kk = 0; kk < 2; kk++){
        int rB = ik * 16 + fr;
        s16x8 bk = *(const s16x8*)(Ks + rB * 64 + (((kk*4 + quad) ^ (rB & 7)) * 8));
        s[ik] = __builtin_amdgcn_mfma_f32_16x16x32_bf16(aq[kk], bk, s[ik], 0, 0, 0);
      }
    }
    __builtin_amdgcn_s_setprio(0);
    const bool diag = (kt == kmax);
    #pragma unroll
    for (int r = 0; r < 4; r++){
      const int qgi = qt * 64 + wrow + quad * 4 + r;
      float tmax = -1e30f;
      #pragma unroll
      for (int ik = 0; ik < 8; ik++){
        float v = s[ik][r] * 0.125f;
        if (diag && (kt * 128 + ik * 16 + fr) > qgi) v = -1e9f;
        s[ik][r] = v;
        tmax = fmaxf(tmax, v);
      }
      #pragma unroll
      for (int off = 8; off >= 1; off >>= 1) tmax = fmaxf(tmax, __shfl_xor(tmax, off));
      const float mnew = fmaxf(m_r[r], tmax);
      const float alpha = __expf(m_r[r] - mnew);
      m_r[r] = mnew;
      float ts = 0.0f;
      const int prow = wrow + quad * 4 + r;
      #pragma unroll
      for (int ik = 0; ik < 8; ik++){
        float p = __expf(s[ik][r] - mnew);
        ts += p;
        Ps[prow * 136 + ik * 16 + fr] = f2bf(p);
      }
      #pragma unroll
      for (int off = 8; off >= 1; off >>= 1) ts += __shfl_xor(ts, off);
      l_r[r] = l_r[r] * alpha + ts;
      #pragma unroll
      for (int jd = 0; jd < 4; jd++) o_acc[jd][r] *= alpha;
    }
    // PV: V fragments straight from global (vt[bh][d][t], L2-hot)
    __builtin_amdgcn_s_setprio(1);
    #pragma unroll
    for (int kk2 = 0; kk2 < 4; kk2++){
      s16x8 ap = *(const s16x8*)(Ps + (wrow + fr) * 136 + kk2 * 32 + quad * 8);
      #pragma unroll
      for (int jd = 0; jd < 4; jd++){
        s16x8 bv = *(const s16x8*)(vgb + (long)(jd * 16 + fr) * T_ + kt * 128 + kk2 * 32 + quad * 8);
        o_acc[jd] = __builtin_amdgcn_mfma_f32_16x16x32_bf16(ap, bv, o_acc[jd], 0, 0, 0);
      }
    }
    __builtin_amdgcn_s_setprio(0);
  }
  #pragma unroll
  for (int r = 0; r < 4; r++){
    const int t_loc = qt * 64 + wrow + quad * 4 + r;
    const long rowbase = ((long)b * T_ + t_loc) * H_ + hh * HD_;
    const float inv = 1.0f / l_r[r];
    #pragma unroll
    for (int jd = 0; jd < 4; jd++)
      att[rowbase + jd * 16 + fr] = f2bf(o_acc[jd][r] * inv);
  }
}

// ---------------------------------------------------------------------------
// Final: h' = h + sum of 4 bf16 partials; rms(h',ln_f) @ head_W + b, clamp,
// softmax/T. grid M_, 256 thr. out = [weights (M_*31), logits (M_*31)]
// ---------------------------------------------------------------------------
__global__ __launch_bounds__(256) void head_kernel(
    const float* __restrict__ hsrc, const u16* __restrict__ pb,
    const float* __restrict__ lnf, const float* __restrict__ hw, const float* __restrict__ hb,
    const float* __restrict__ temp, float* __restrict__ outp)
{
  const int m = blockIdx.x, t = threadIdx.x;
  __shared__ float lat[H_];
  __shared__ float red[4];
  __shared__ float part[8][32];
  float4 v = ((const float4*)(hsrc + (long)m * H_))[t];
  #pragma unroll
  for (int k = 0; k < 4; k++){
    u16x4 a = *(const u16x4*)(pb + (long)k * M_ * H_ + (long)m * H_ + t * 4);
    v.x += bf2f(a[0]); v.y += bf2f(a[1]); v.z += bf2f(a[2]); v.w += bf2f(a[3]);
  }
  float ss = v.x*v.x + v.y*v.y + v.z*v.z + v.w*v.w;
  #pragma unroll
  for (int off = 32; off >= 1; off >>= 1) ss += __shfl_xor(ss, off);
  if ((t & 63) == 0) red[t >> 6] = ss;
  __syncthreads();
  const float scale = rsqrtf((red[0]+red[1]+red[2]+red[3]) * (1.0f/H_) + 1e-6f);
  const float4 wv = ((const float4*)lnf)[t];
  lat[t*4+0] = v.x*scale*wv.x;  lat[t*4+1] = v.y*scale*wv.y;
  lat[t*4+2] = v.z*scale*wv.z;  lat[t*4+3] = v.w*scale*wv.w;
  __syncthreads();
  const int j = t & 31, seg = t >> 5;
  float pp = 0.0f;
  if (j < 31){
    const float* wp = hw + j;
    for (int k = seg * 128; k < seg * 128 + 128; k++) pp += lat[k] * wp[(long)k * 31];
  }
  part[seg][j] = pp;
  __syncthreads();
  if (t < 32){
    float dot = 0.0f;
    #pragma unroll
    for (int s2 = 0; s2 < 8; s2++) dot += part[s2][t];
    const float logit = (t < 31) ? dot + hb[t] : -1e30f;
    const float lc = fminf(fmaxf(logit, -10.0f), 10.0f);
    const float z = (t < 31) ? lc / temp[0] : -1e30f;
    float mx = z;
    #pragma unroll
    for (int off = 16; off >= 1; off >>= 1) mx = fmaxf(mx, __shfl_xor(mx, off, 32));
    const float e = (t < 31) ? __expf(z - mx) : 0.0f;
    float sum = e;
    #pragma unroll
    for (int off = 16; off >= 1; off >>= 1) sum += __shfl_xor(sum, off, 32);
    if (t < 31){
      outp[(long)m * NTP1_ + t] = e / sum;
      outp[(long)M_ * NTP1_ + (long)m * NTP1_ + t] = lc;
    }
  }
}

// ---------------------------------------------------------------------------
extern "C" void kernel_launch(void* const* d_in, const int* in_sizes, int n_in,
                              void* d_out, int out_size, void* d_ws, size_t ws_size,
                              hipStream_t stream) {
  const float* x    = (const float*)d_in[0];
  const float* temp = (const float*)d_in[1];
  const float* sW   = (const float*)d_in[2];
  const float* sb   = (const float*)d_in[3];
  const float* ln1  = (const float*)d_in[4];
  const float* ln2  = (const float*)d_in[5];
  const float* Wqkv = (const float*)d_in[6];
  const float* Aqkv = (const float*)d_in[7];
  const float* Bqkv = (const float*)d_in[8];
  const float* Wo   = (const float*)d_in[9];
  const float* Ao   = (const float*)d_in[10];
  const float* Bo   = (const float*)d_in[11];
  const float* Wgu  = (const float*)d_in[12];
  const float* Agu  = (const float*)d_in[13];
  const float* Bgu  = (const float*)d_in[14];
  const float* Wd   = (const float*)d_in[15];
  const float* Ad   = (const float*)d_in[16];
  const float* Bd   = (const float*)d_in[17];
  const float* lnf  = (const float*)d_in[18];
  const float* hW   = (const float*)d_in[19];
  const float* hb   = (const float*)d_in[20];
  float* out = (float*)d_out;

  uint8_t* ws = (uint8_t*)d_ws;
  size_t off = 0;
  auto alloc = [&](size_t bytes) -> void* {
    void* p = ws + off;
    off += (bytes + 255) & ~(size_t)255;
    return p;
  };
  u16*   wt_qkv = (u16*)  alloc((size_t)L_ * 3 * H_ * H_ * 2);
  u16*   wt_o   = (u16*)  alloc((size_t)L_ * H_ * H_ * 2);
  u16*   wt_gu  = (u16*)  alloc((size_t)L_ * 2 * F_ * H_ * 2);
  u16*   wt_d   = (u16*)  alloc((size_t)L_ * H_ * F_ * 2);
  float* h      = (float*)alloc((size_t)M_ * H_ * 4);
  u16*   hn     = (u16*)  alloc((size_t)M_ * H_ * 2);
  u16*   pb16   = (u16*)  alloc((size_t)4 * M_ * H_ * 2);   // bf16 split-K partials
  u16*   qr     = (u16*)  alloc((size_t)M_ * H_ * 2);
  u16*   krr    = (u16*)  alloc((size_t)M_ * H_ * 2);
  u16*   vtb    = (u16*)  alloc((size_t)M_ * H_ * 2);
  u16*   attb   = (u16*)  alloc((size_t)M_ * H_ * 2);
  u16*   actb   = (u16*)  alloc((size_t)M_ * F_ * 2);

  // single prep dispatch: all weight folds + embed
  prep_kernel<<<27136, 256, 0, stream>>>(
      Wqkv, Aqkv, Bqkv, wt_qkv, Wo, Ao, Bo, wt_o,
      Wgu, Agu, Bgu, wt_gu, Wd, Ad, Bd, wt_d, x, sW, sb, h);

  for (int l = 0; l < L_; l++){
    // h += d-partials of previous layer (l>0, 4 bf16 partials), then rms -> hn
    rms_kernel<<<M_ / 4, 256, 0, stream>>>(h, pb16, ln1 + (long)l * H_, hn, l > 0 ? 4 : 0);
    // qkv GEMM with fused rope + v-transpose epilogue
    gemm_qkv<<<dim3(16, 24), 256, 0, stream>>>(hn, wt_qkv + (long)l * 3 * H_ * H_,
        qr, krr, vtb);
    attn_kernel<<<dim3(16, B_ * NH_), 256, 0, stream>>>(qr, krr, vtb, attb);
    // o-proj: split-K=4 bf16 partials into pb16[0..3] (Ksteps=16 over Z=4)
    gemm_bt<1><<<dim3(16, 8, 4), 256, 0, stream>>>(attb, wt_o + (long)l * H_ * H_,
        pb16, H_, H_, 16, (long)M_ * H_);
    // h += o-partials (4), rms -> hn
    rms_kernel<<<M_ / 4, 256, 0, stream>>>(h, pb16, ln2 + (long)l * H_, hn, 4);
    // fused gate/up GEMM + silu -> actb (bf16), 128x64 tiles
    gemm_gu<<<dim3(16, 44), 256, 0, stream>>>(hn,
        wt_gu + (long)l * 2 * F_ * H_, wt_gu + (long)l * 2 * F_ * H_ + (long)F_ * H_, actb);
    // down-proj: split-K=4 bf16 partials into pb16[0..3] (Ksteps=44 over Z=4)
    gemm_bt<1><<<dim3(16, 8, 4), 256, 0, stream>>>(actb, wt_d + (long)l * H_ * F_,
        pb16, H_, F_, 44, (long)M_ * H_);
  }

  head_kernel<<<M_, 256, 0, stream>>>(h, pb16, lnf, hW, hb, temp, out);
}

// Round 4
// 1483.312 us; speedup vs baseline: 1.0956x; 1.0956x over previous
//
#include <hip/hip_runtime.h>
#include <hip/hip_bf16.h>
#include <cstdint>

// Shapes (compile-time constants for this problem)
#define B_    2
#define T_    1024
#define NT_   30
#define H_    1024
#define L_    8
#define F_    2816
#define NH_   16
#define R_    16
#define HD_   64
#define M_    2048          // B*T
#define NTP1_ 31

typedef unsigned short u16;
typedef short  s16x8 __attribute__((ext_vector_type(8)));   // MFMA bf16 operand
typedef unsigned short u16x4 __attribute__((ext_vector_type(4)));
typedef unsigned short u16x8 __attribute__((ext_vector_type(8)));
typedef float  f32x4 __attribute__((ext_vector_type(4)));

__device__ __forceinline__ u16 f2bf(float f){
  __hip_bfloat16 h = __float2bfloat16(f);
  return __builtin_bit_cast(unsigned short, h);
}
__device__ __forceinline__ float bf2f(u16 u){
  uint32_t v = (uint32_t)u << 16;
  return __builtin_bit_cast(float, v);
}

__device__ __forceinline__ void async16(const void* g, void* l){
  __builtin_amdgcn_global_load_lds((const __attribute__((address_space(1))) void*)g,
                                   (__attribute__((address_space(3))) void*)l, 16, 0, 0);
}

// ---------------------------------------------------------------------------
// Unified prep: fold all 4 LoRA weight groups (bf16, transposed) + embed,
// one dispatch.  Wt[n][k] = W[k][n] + 2 * sum_r A[r][k] * Bm[n][r]
// block map: [0,6144) qkv fold, [6144,8192) o fold, [8192,19456) gu fold,
// [19456,25088) d fold, [25088,27136) embed rows.
// launch_bounds(256,6): LDS 26KB*6=157KB fits -> 6 blocks/CU to hide the
// strided-W global-load latency (counters: 38% occ, 31% HBM, 30% VALU).
// ---------------------------------------------------------------------------
struct FoldSmem {
  float Wt_s[64][65];   // [n][k]
  float As[16][64];     // [r][k]
  float Bs[64][20];     // [n][r]
};

__device__ __forceinline__ void fold_tile(
    const float* __restrict__ W, const float* __restrict__ A,
    const float* __restrict__ Bm, u16* __restrict__ Wt,
    int K, int N, int k0, int n0, FoldSmem& sm)
{
  const int tid = threadIdx.x;
  {
    const int kr = tid >> 4;
    const int n4 = (tid & 15) * 4;
    #pragma unroll
    for (int p = 0; p < 4; p++){
      int krow = p * 16 + kr;
      float4 w = *(const float4*)(W + (long)(k0 + krow) * N + n0 + n4);
      sm.Wt_s[n4+0][krow] = w.x; sm.Wt_s[n4+1][krow] = w.y;
      sm.Wt_s[n4+2][krow] = w.z; sm.Wt_s[n4+3][krow] = w.w;
    }
    const int r = tid >> 4, kc = (tid & 15) * 4;
    *(float4*)&sm.As[r][kc] = *(const float4*)(A + (long)r * K + k0 + kc);
    const int nb = tid >> 2, r4 = (tid & 3) * 4;
    float4 b = *(const float4*)(Bm + (long)(n0 + nb) * 16 + r4);
    sm.Bs[nb][r4+0]=b.x; sm.Bs[nb][r4+1]=b.y; sm.Bs[nb][r4+2]=b.z; sm.Bs[nb][r4+3]=b.w;
  }
  __syncthreads();
  const int ko = (tid & 7) * 8;
  const int na = tid >> 3;
  float bq0[16], bq1[16];
  #pragma unroll
  for (int c = 0; c < 4; c++){
    *(float4*)&bq0[c*4] = *(const float4*)&sm.Bs[na][c*4];
    *(float4*)&bq1[c*4] = *(const float4*)&sm.Bs[na+32][c*4];
  }
  float l0[8] = {}, l1[8] = {};
  #pragma unroll
  for (int r = 0; r < 16; r++){
    float a[8];
    *(float4*)&a[0] = *(const float4*)&sm.As[r][ko];
    *(float4*)&a[4] = *(const float4*)&sm.As[r][ko+4];
    #pragma unroll
    for (int j = 0; j < 8; j++){
      l0[j] += a[j] * bq0[r];
      l1[j] += a[j] * bq1[r];
    }
  }
  u16x8 o0, o1;
  #pragma unroll
  for (int j = 0; j < 8; j++){
    o0[j] = f2bf(sm.Wt_s[na][ko+j]    + 2.0f * l0[j]);
    o1[j] = f2bf(sm.Wt_s[na+32][ko+j] + 2.0f * l1[j]);
  }
  *(u16x8*)(Wt + (long)(n0+na)*K    + k0 + ko) = o0;
  *(u16x8*)(Wt + (long)(n0+na+32)*K + k0 + ko) = o1;
}

__global__ __launch_bounds__(256, 6) void prep_kernel(
    const float* __restrict__ Wqkv, const float* __restrict__ Aqkv,
    const float* __restrict__ Bqkv, u16* __restrict__ wt_qkv,
    const float* __restrict__ Wo, const float* __restrict__ Ao,
    const float* __restrict__ Bo, u16* __restrict__ wt_o,
    const float* __restrict__ Wgu, const float* __restrict__ Agu,
    const float* __restrict__ Bgu, u16* __restrict__ wt_gu,
    const float* __restrict__ Wd, const float* __restrict__ Ad,
    const float* __restrict__ Bd, u16* __restrict__ wt_d,
    const float* __restrict__ x, const float* __restrict__ sw,
    const float* __restrict__ sb, float* __restrict__ h)
{
  __shared__ FoldSmem sm;
  const int id = blockIdx.x;
  if (id < 25088){
    const float *W, *A, *Bm; u16* Wt; int K, N, k0, n0;
    if (id < 6144){               // qkv: 24 mats x (16k x 16n)
      int z = id >> 8, r = id & 255;
      W = Wqkv + (long)z * 1048576; A = Aqkv + (long)z * 16384;
      Bm = Bqkv + (long)z * 16384; Wt = wt_qkv + (long)z * 1048576;
      K = 1024; N = 1024; k0 = (r & 15) * 64; n0 = (r >> 4) * 64;
    } else if (id < 8192){        // o: 8 mats x (16k x 16n)
      int t = id - 6144; int z = t >> 8, r = t & 255;
      W = Wo + (long)z * 1048576; A = Ao + (long)z * 16384;
      Bm = Bo + (long)z * 16384;  Wt = wt_o + (long)z * 1048576;
      K = 1024; N = 1024; k0 = (r & 15) * 64; n0 = (r >> 4) * 64;
    } else if (id < 19456){       // gu: 16 mats x (16k x 44n)
      int t = id - 8192; int z = t / 704, r = t % 704;
      W = Wgu + (long)z * 2883584; A = Agu + (long)z * 16384;
      Bm = Bgu + (long)z * 45056;  Wt = wt_gu + (long)z * 2883584;
      K = 1024; N = 2816; k0 = (r % 16) * 64; n0 = (r / 16) * 64;
    } else {                      // d: 8 mats x (44k x 16n)
      int t = id - 19456; int z = t / 704, r = t % 704;
      W = Wd + (long)z * 2883584; A = Ad + (long)z * 45056;
      Bm = Bd + (long)z * 16384;  Wt = wt_d + (long)z * 2883584;
      K = 2816; N = 1024; k0 = (r % 44) * 64; n0 = (r / 44) * 64;
    }
    fold_tile(W, A, Bm, Wt, K, N, k0, n0, sm);
  } else {                        // embed rows
    const int m = id - 25088;
    const float* xr = x + (long)m * NT_;
    for (int jj = threadIdx.x; jj < H_; jj += 256){
      float acc = sb[jj];
      #pragma unroll
      for (int i = 0; i < NT_; i++) acc += xr[i] * sw[i * H_ + jj];
      h[(long)m * H_ + jj] = acc;
    }
  }
}

// ---------------------------------------------------------------------------
// RMSNorm row -> bf16, optionally fusing h += sum of nparts bf16 split-K
// partials (pb strided M_*H_), writing h back. grid M_, 256 thr.
// ---------------------------------------------------------------------------
__global__ __launch_bounds__(256) void rms_kernel(
    float* __restrict__ hsrc, const u16* __restrict__ pb,
    const float* __restrict__ w, u16* __restrict__ outp, int nparts)
{
  const int m = blockIdx.x, t = threadIdx.x;
  float4 v = ((const float4*)(hsrc + (long)m * H_))[t];
  if (nparts){
    for (int k = 0; k < nparts; k++){
      u16x4 a = *(const u16x4*)(pb + (long)k * M_ * H_ + (long)m * H_ + t * 4);
      v.x += bf2f(a[0]); v.y += bf2f(a[1]); v.z += bf2f(a[2]); v.w += bf2f(a[3]);
    }
    ((float4*)(hsrc + (long)m * H_))[t] = v;
  }
  float ss = v.x*v.x + v.y*v.y + v.z*v.z + v.w*v.w;
  #pragma unroll
  for (int off = 32; off >= 1; off >>= 1) ss += __shfl_xor(ss, off);
  __shared__ float red[4];
  if ((t & 63) == 0) red[t >> 6] = ss;
  __syncthreads();
  const float scale = rsqrtf((red[0]+red[1]+red[2]+red[3]) * (1.0f/H_) + 1e-6f);
  const float4 wv = ((const float4*)w)[t];
  u16x4 o;
  o[0] = f2bf(v.x*scale*wv.x); o[1] = f2bf(v.y*scale*wv.y);
  o[2] = f2bf(v.z*scale*wv.z); o[3] = f2bf(v.w*scale*wv.w);
  *(u16x4*)(outp + (long)m * H_ + t * 4) = o;
}

// ---------------------------------------------------------------------------
// GEMM: C[m][n] = A(M,K)bf16 @ Bt(N,K)bf16^T.  OUTBF=1 -> bf16 out, 0 -> fp32.
// m97 structure: BK=64, 2-barrier K-loop, global_load_lds width-16 staging.
// Split-K over gridDim.z. grid (M/128, N/128, Z), 256 thr, 3 blocks/CU.
// ---------------------------------------------------------------------------
template<int OUTBF>
__global__ __launch_bounds__(256, 3) void gemm_bt(
    const u16* __restrict__ Ag, const u16* __restrict__ Btg, void* __restrict__ Cptr,
    int Ndim, int Kstride, int Ksteps, long zsC)
{
  const int z = blockIdx.z, Z = (int)gridDim.z;
  const int kb = Ksteps / Z, rem = Ksteps % Z;
  const int sblk = (z < rem) ? z * (kb + 1) : rem * (kb + 1) + (z - rem) * kb;
  const int klen = (kb + (z < rem ? 1 : 0)) * 64;
  Ag  += (long)sblk * 64;
  Btg += (long)sblk * 64;
  const int m0 = blockIdx.x * 128, n0 = blockIdx.y * 128;
  __shared__ alignas(16) u16 As[128 * 64];
  __shared__ alignas(16) u16 Bs[128 * 64];
  const int tid = threadIdx.x;
  const int wave = tid >> 6, lane = tid & 63;
  const int wm = (wave & 1) * 64, wn = (wave >> 1) * 64;
  const int fr = lane & 15, quad = lane >> 4;

  f32x4 acc[4][4] = {};

  for (int kt = 0; kt < klen; kt += 64){
    __syncthreads();
    #pragma unroll
    for (int c = 0; c < 4; c++){
      int lin = c * 256 + tid;
      int row = lin >> 3, p = lin & 7;
      int gc = ((p ^ (row & 7)) * 8);
      async16(Ag  + (long)(m0 + row) * Kstride + kt + gc, As + lin * 8);
      async16(Btg + (long)(n0 + row) * Kstride + kt + gc, Bs + lin * 8);
    }
    __syncthreads();
    #pragma unroll
    for (int kk = 0; kk < 2; kk++){
      s16x8 af[4], bg[4];
      #pragma unroll
      for (int i = 0; i < 4; i++){
        int rA = wm + i * 16 + fr;
        af[i] = *(const s16x8*)(As + rA * 64 + (((kk*4 + quad) ^ (rA & 7)) * 8));
        int rB = wn + i * 16 + fr;
        bg[i] = *(const s16x8*)(Bs + rB * 64 + (((kk*4 + quad) ^ (rB & 7)) * 8));
      }
      #pragma unroll
      for (int i = 0; i < 4; i++)
        #pragma unroll
        for (int j = 0; j < 4; j++)
          acc[i][j] = __builtin_amdgcn_mfma_f32_16x16x32_bf16(af[i], bg[j], acc[i][j], 0, 0, 0);
    }
  }
  #pragma unroll
  for (int i = 0; i < 4; i++){
    int row0 = m0 + wm + i * 16 + quad * 4;
    #pragma unroll
    for (int j = 0; j < 4; j++){
      int col = n0 + wn + j * 16 + fr;
      #pragma unroll
      for (int r = 0; r < 4; r++){
        long idx = (long)(row0 + r) * Ndim + col;
        if (OUTBF){
          u16* C = (u16*)Cptr + (long)blockIdx.z * zsC;
          C[idx] = f2bf(acc[i][j][r]);
        } else {
          float* C = (float*)Cptr + (long)blockIdx.z * zsC;
          C[idx] = acc[i][j][r];
        }
      }
    }
  }
}

// ---------------------------------------------------------------------------
// qkv GEMM with fused RoPE (q,k) + V-transpose epilogue.
// A = hn (M,1024) bf16, Bt = wt_qkv (3072,1024) bf16 n-major.
// grid (16, 24): by 0..7 -> q, 8..15 -> k, 16..23 -> v (uniform per block).
// ---------------------------------------------------------------------------
__global__ __launch_bounds__(256, 3) void gemm_qkv(
    const u16* __restrict__ Ag, const u16* __restrict__ Btg,
    u16* __restrict__ qr, u16* __restrict__ kr, u16* __restrict__ vt)
{
  const int m0 = blockIdx.x * 128, n0 = blockIdx.y * 128;
  __shared__ alignas(16) u16 As[128 * 64];
  __shared__ alignas(16) u16 Bs[128 * 64];
  const int tid = threadIdx.x;
  const int wave = tid >> 6, lane = tid & 63;
  const int wm = (wave & 1) * 64, wn = (wave >> 1) * 64;
  const int fr = lane & 15, quad = lane >> 4;

  f32x4 acc[4][4] = {};

  for (int kt = 0; kt < H_; kt += 64){
    __syncthreads();
    #pragma unroll
    for (int c = 0; c < 4; c++){
      int lin = c * 256 + tid;
      int row = lin >> 3, p = lin & 7;
      int gc = ((p ^ (row & 7)) * 8);
      async16(Ag  + (long)(m0 + row) * H_ + kt + gc, As + lin * 8);
      async16(Btg + (long)(n0 + row) * H_ + kt + gc, Bs + lin * 8);
    }
    __syncthreads();
    #pragma unroll
    for (int kk = 0; kk < 2; kk++){
      s16x8 af[4], bg[4];
      #pragma unroll
      for (int i = 0; i < 4; i++){
        int rA = wm + i * 16 + fr;
        af[i] = *(const s16x8*)(As + rA * 64 + (((kk*4 + quad) ^ (rA & 7)) * 8));
        int rB = wn + i * 16 + fr;
        bg[i] = *(const s16x8*)(Bs + rB * 64 + (((kk*4 + quad) ^ (rB & 7)) * 8));
      }
      #pragma unroll
      for (int i = 0; i < 4; i++)
        #pragma unroll
        for (int j = 0; j < 4; j++)
          acc[i][j] = __builtin_amdgcn_mfma_f32_16x16x32_bf16(af[i], bg[j], acc[i][j], 0, 0, 0);
    }
  }
  const int sel  = n0 >> 10;               // 0=q 1=k 2=v
  const int nloc = (n0 & 1023) + wn;       // within-matrix col base of this wave
  const int hh   = nloc >> 6;              // head index (wave-uniform)
  if (sel == 2){
    #pragma unroll
    for (int i = 0; i < 4; i++){
      int row0 = m0 + wm + i * 16 + quad * 4;
      int b = row0 >> 10, t0 = row0 & 1023;
      #pragma unroll
      for (int j = 0; j < 4; j++){
        int d = j * 16 + fr;
        u16x4 o;
        #pragma unroll
        for (int r = 0; r < 4; r++) o[r] = f2bf(acc[i][j][r]);
        *(u16x4*)(vt + ((long)((b * NH_ + hh) * HD_ + d)) * T_ + t0) = o;
      }
    }
  } else {
    u16* dst = sel ? kr : qr;
    #pragma unroll
    for (int i = 0; i < 4; i++){
      int row0 = m0 + wm + i * 16 + quad * 4;
      int b = row0 >> 10;
      #pragma unroll
      for (int j = 0; j < 2; j++){
        int d1 = j * 16 + fr;                    // 0..31
        float freq = exp2f((float)d1 * (-13.287712379549449f / 32.0f)); // 10000^(-d1/32)
        #pragma unroll
        for (int r = 0; r < 4; r++){
          int t = (row0 + r) & 1023;
          float x1 = acc[i][j][r], x2 = acc[i][j + 2][r];
          float sn, cs; __sincosf((float)t * freq, &sn, &cs);
          long base = ((long)(b * NH_ + hh) * T_ + t) * HD_;
          dst[base + d1]      = f2bf(x1 * cs - x2 * sn);
          dst[base + d1 + 32] = f2bf(x2 * cs + x1 * sn);
        }
      }
    }
  }
}

// ---------------------------------------------------------------------------
// Fused gate/up GEMM + SiLU, 128x64 tile: act[m][n] = silu(A@Wg^T)*(A@Wu^T).
// grid (M/128, F/64), 256 thr, 3 blocks/CU.
// ---------------------------------------------------------------------------
__global__ __launch_bounds__(256, 3) void gemm_gu(
    const u16* __restrict__ Ag, const u16* __restrict__ Bgw,
    const u16* __restrict__ Buw, u16* __restrict__ actb)
{
  const int m0 = blockIdx.x * 128, n0 = blockIdx.y * 64;
  __shared__ alignas(16) u16 As[128 * 64];
  __shared__ alignas(16) u16 Bg_[64 * 64];
  __shared__ alignas(16) u16 Bu_[64 * 64];
  const int tid = threadIdx.x;
  const int wave = tid >> 6, lane = tid & 63;
  const int wm = (wave & 1) * 64, wn = (wave >> 1) * 32;
  const int fr = lane & 15, quad = lane >> 4;

  f32x4 accg[4][2] = {}, accu[4][2] = {};

  for (int kt = 0; kt < H_; kt += 64){
    __syncthreads();
    #pragma unroll
    for (int c = 0; c < 4; c++){
      int lin = c * 256 + tid;
      int row = lin >> 3, p = lin & 7;
      async16(Ag + (long)(m0 + row) * H_ + kt + ((p ^ (row & 7)) * 8), As + lin * 8);
    }
    #pragma unroll
    for (int c = 0; c < 2; c++){
      int lin = c * 256 + tid;
      int row = lin >> 3, p = lin & 7;
      int gc = ((p ^ (row & 7)) * 8);
      async16(Bgw + (long)(n0 + row) * H_ + kt + gc, Bg_ + lin * 8);
      async16(Buw + (long)(n0 + row) * H_ + kt + gc, Bu_ + lin * 8);
    }
    __syncthreads();
    #pragma unroll
    for (int kk = 0; kk < 2; kk++){
      s16x8 af[4], bg[2], bu[2];
      #pragma unroll
      for (int i = 0; i < 4; i++){
        int rA = wm + i * 16 + fr;
        af[i] = *(const s16x8*)(As + rA * 64 + (((kk*4 + quad) ^ (rA & 7)) * 8));
      }
      #pragma unroll
      for (int j = 0; j < 2; j++){
        int rB = wn + j * 16 + fr;
        bg[j] = *(const s16x8*)(Bg_ + rB * 64 + (((kk*4 + quad) ^ (rB & 7)) * 8));
        bu[j] = *(const s16x8*)(Bu_ + rB * 64 + (((kk*4 + quad) ^ (rB & 7)) * 8));
      }
      #pragma unroll
      for (int i = 0; i < 4; i++)
        #pragma unroll
        for (int j = 0; j < 2; j++){
          accg[i][j] = __builtin_amdgcn_mfma_f32_16x16x32_bf16(af[i], bg[j], accg[i][j], 0, 0, 0);
          accu[i][j] = __builtin_amdgcn_mfma_f32_16x16x32_bf16(af[i], bu[j], accu[i][j], 0, 0, 0);
        }
    }
  }
  #pragma unroll
  for (int i = 0; i < 4; i++){
    int row0 = m0 + wm + i * 16 + quad * 4;
    #pragma unroll
    for (int j = 0; j < 2; j++){
      int col = n0 + wn + j * 16 + fr;
      #pragma unroll
      for (int r = 0; r < 4; r++){
        float g = accg[i][j][r], u = accu[i][j][r];
        float act = g / (1.0f + __expf(-g)) * u;
        actb[(long)(row0 + r) * F_ + col] = f2bf(act);
      }
    }
  }
}

// ---------------------------------------------------------------------------
// Flash attention: grid (16, B_*NH_), 256 thr. One q-tile per block.
// Q direct from global (zero reuse, even across waves). K and V LDS-staged
// (4x cross-wave reuse; round-3 V-direct was scattered-L2-latency-bound and
// regressed). LDS 49.4KB -> 3 blocks/CU.
// qt reversed for b=1 so co-resident blocks pair qt with 15-qt: balanced.
// ---------------------------------------------------------------------------
__global__ __launch_bounds__(256, 3) void attn_kernel(
    const u16* __restrict__ qr, const u16* __restrict__ kr,
    const u16* __restrict__ vt, u16* __restrict__ att)
{
  const int bh = blockIdx.y;
  const int b = bh >> 4, hh = bh & 15;
  const int qt = b ? (15 - (int)blockIdx.x) : (int)blockIdx.x;
  __shared__ alignas(16) u16 Ks[128 * 64];
  __shared__ alignas(16) u16 Vs[64 * 128];
  __shared__ alignas(16) u16 Ps[64 * 136];
  const int tid = threadIdx.x;
  const int wave = tid >> 6, lane = tid & 63, fr = lane & 15, quad = lane >> 4;
  const int wrow = wave * 16;
  const u16* kgb = kr + (long)bh * T_ * HD_;
  const u16* vgb = vt + (long)bh * HD_ * T_;
  const u16* qg  = qr + ((long)bh * T_ + qt * 64) * HD_;

  // Q fragments straight from global (row wrow+fr, col chunk (kk*4+quad)*8)
  s16x8 aq[2];
  #pragma unroll
  for (int kk = 0; kk < 2; kk++)
    aq[kk] = *(const s16x8*)(qg + (wrow + fr) * HD_ + kk * 32 + quad * 8);

  f32x4 o_acc[4] = {};
  float m_r[4] = {-1e30f, -1e30f, -1e30f, -1e30f};
  float l_r[4] = {};
  const int kmax = (qt * 64 + 63) >> 7;

  for (int kt = 0; kt <= kmax; kt++){
    __syncthreads();
    const u16* kg = kgb + (long)kt * 128 * HD_;
    #pragma unroll
    for (int c = 0; c < 4; c++){
      int lin = c * 256 + tid, row = lin >> 3, p = lin & 7;
      async16(kg + row * HD_ + ((p ^ (row & 7)) * 8), Ks + lin * 8);
    }
    #pragma unroll
    for (int c = 0; c < 4; c++){
      int lin = c * 256 + tid, row = lin >> 4, p = lin & 15;
      async16(vgb + (long)row * T_ + kt * 128 + ((p ^ (row & 15)) * 8), Vs + lin * 8);
    }
    __syncthreads();

    f32x4 s[8] = {};
    __builtin_amdgcn_s_setprio(1);
    #pragma unroll
    for (int ik = 0; ik < 8; ik++){
      #pragma unroll
      for (int kk = 0; kk < 2; kk++){
        int rB = ik * 16 + fr;
        s16x8 bk = *(const s16x8*)(Ks + rB * 64 + (((kk*4 + quad) ^ (rB & 7)) * 8));
        s[ik] = __builtin_amdgcn_mfma_f32_16x16x32_bf16(aq[kk], bk, s[ik], 0, 0, 0);
      }
    }
    __builtin_amdgcn_s_setprio(0);
    const bool diag = (kt == kmax);
    #pragma unroll
    for (int r = 0; r < 4; r++){
      const int qgi = qt * 64 + wrow + quad * 4 + r;
      float tmax = -1e30f;
      #pragma unroll
      for (int ik = 0; ik < 8; ik++){
        float v = s[ik][r] * 0.125f;
        if (diag && (kt * 128 + ik * 16 + fr) > qgi) v = -1e9f;
        s[ik][r] = v;
        tmax = fmaxf(tmax, v);
      }
      #pragma unroll
      for (int off = 8; off >= 1; off >>= 1) tmax = fmaxf(tmax, __shfl_xor(tmax, off));
      const float mnew = fmaxf(m_r[r], tmax);
      const float alpha = __expf(m_r[r] - mnew);
      m_r[r] = mnew;
      float ts = 0.0f;
      const int prow = wrow + quad * 4 + r;
      #pragma unroll
      for (int ik = 0; ik < 8; ik++){
        float p = __expf(s[ik][r] - mnew);
        ts += p;
        Ps[prow * 136 + ik * 16 + fr] = f2bf(p);
      }
      #pragma unroll
      for (int off = 8; off >= 1; off >>= 1) ts += __shfl_xor(ts, off);
      l_r[r] = l_r[r] * alpha + ts;
      #pragma unroll
      for (int jd = 0; jd < 4; jd++) o_acc[jd][r] *= alpha;
    }
    __builtin_amdgcn_s_setprio(1);
    #pragma unroll
    for (int kk2 = 0; kk2 < 4; kk2++){
      s16x8 ap = *(const s16x8*)(Ps + (wrow + fr) * 136 + kk2 * 32 + quad * 8);
      #pragma unroll
      for (int jd = 0; jd < 4; jd++){
        int rV = jd * 16 + fr;
        s16x8 bv = *(const s16x8*)(Vs + rV * 128 + (((kk2*4 + quad) ^ (rV & 15)) * 8));
        o_acc[jd] = __builtin_amdgcn_mfma_f32_16x16x32_bf16(ap, bv, o_acc[jd], 0, 0, 0);
      }
    }
    __builtin_amdgcn_s_setprio(0);
  }
  #pragma unroll
  for (int r = 0; r < 4; r++){
    const int t_loc = qt * 64 + wrow + quad * 4 + r;
    const long rowbase = ((long)b * T_ + t_loc) * H_ + hh * HD_;
    const float inv = 1.0f / l_r[r];
    #pragma unroll
    for (int jd = 0; jd < 4; jd++)
      att[rowbase + jd * 16 + fr] = f2bf(o_acc[jd][r] * inv);
  }
}

// ---------------------------------------------------------------------------
// Final: h' = h + sum of 4 bf16 partials; rms(h',ln_f) @ head_W + b, clamp,
// softmax/T. grid M_, 256 thr. out = [weights (M_*31), logits (M_*31)]
// ---------------------------------------------------------------------------
__global__ __launch_bounds__(256) void head_kernel(
    const float* __restrict__ hsrc, const u16* __restrict__ pb,
    const float* __restrict__ lnf, const float* __restrict__ hw, const float* __restrict__ hb,
    const float* __restrict__ temp, float* __restrict__ outp)
{
  const int m = blockIdx.x, t = threadIdx.x;
  __shared__ float lat[H_];
  __shared__ float red[4];
  __shared__ float part[8][32];
  float4 v = ((const float4*)(hsrc + (long)m * H_))[t];
  #pragma unroll
  for (int k = 0; k < 4; k++){
    u16x4 a = *(const u16x4*)(pb + (long)k * M_ * H_ + (long)m * H_ + t * 4);
    v.x += bf2f(a[0]); v.y += bf2f(a[1]); v.z += bf2f(a[2]); v.w += bf2f(a[3]);
  }
  float ss = v.x*v.x + v.y*v.y + v.z*v.z + v.w*v.w;
  #pragma unroll
  for (int off = 32; off >= 1; off >>= 1) ss += __shfl_xor(ss, off);
  if ((t & 63) == 0) red[t >> 6] = ss;
  __syncthreads();
  const float scale = rsqrtf((red[0]+red[1]+red[2]+red[3]) * (1.0f/H_) + 1e-6f);
  const float4 wv = ((const float4*)lnf)[t];
  lat[t*4+0] = v.x*scale*wv.x;  lat[t*4+1] = v.y*scale*wv.y;
  lat[t*4+2] = v.z*scale*wv.z;  lat[t*4+3] = v.w*scale*wv.w;
  __syncthreads();
  const int j = t & 31, seg = t >> 5;
  float pp = 0.0f;
  if (j < 31){
    const float* wp = hw + j;
    for (int k = seg * 128; k < seg * 128 + 128; k++) pp += lat[k] * wp[(long)k * 31];
  }
  part[seg][j] = pp;
  __syncthreads();
  if (t < 32){
    float dot = 0.0f;
    #pragma unroll
    for (int s2 = 0; s2 < 8; s2++) dot += part[s2][t];
    const float logit = (t < 31) ? dot + hb[t] : -1e30f;
    const float lc = fminf(fmaxf(logit, -10.0f), 10.0f);
    const float z = (t < 31) ? lc / temp[0] : -1e30f;
    float mx = z;
    #pragma unroll
    for (int off = 16; off >= 1; off >>= 1) mx = fmaxf(mx, __shfl_xor(mx, off, 32));
    const float e = (t < 31) ? __expf(z - mx) : 0.0f;
    float sum = e;
    #pragma unroll
    for (int off = 16; off >= 1; off >>= 1) sum += __shfl_xor(sum, off, 32);
    if (t < 31){
      outp[(long)m * NTP1_ + t] = e / sum;
      outp[(long)M_ * NTP1_ + (long)m * NTP1_ + t] = lc;
    }
  }
}

// ---------------------------------------------------------------------------
extern "C" void kernel_launch(void* const* d_in, const int* in_sizes, int n_in,
                              void* d_out, int out_size, void* d_ws, size_t ws_size,
                              hipStream_t stream) {
  const float* x    = (const float*)d_in[0];
  const float* temp = (const float*)d_in[1];
  const float* sW   = (const float*)d_in[2];
  const float* sb   = (const float*)d_in[3];
  const float* ln1  = (const float*)d_in[4];
  const float* ln2  = (const float*)d_in[5];
  const float* Wqkv = (const float*)d_in[6];
  const float* Aqkv = (const float*)d_in[7];
  const float* Bqkv = (const float*)d_in[8];
  const float* Wo   = (const float*)d_in[9];
  const float* Ao   = (const float*)d_in[10];
  const float* Bo   = (const float*)d_in[11];
  const float* Wgu  = (const float*)d_in[12];
  const float* Agu  = (const float*)d_in[13];
  const float* Bgu  = (const float*)d_in[14];
  const float* Wd   = (const float*)d_in[15];
  const float* Ad   = (const float*)d_in[16];
  const float* Bd   = (const float*)d_in[17];
  const float* lnf  = (const float*)d_in[18];
  const float* hW   = (const float*)d_in[19];
  const float* hb   = (const float*)d_in[20];
  float* out = (float*)d_out;

  uint8_t* ws = (uint8_t*)d_ws;
  size_t off = 0;
  auto alloc = [&](size_t bytes) -> void* {
    void* p = ws + off;
    off += (bytes + 255) & ~(size_t)255;
    return p;
  };
  u16*   wt_qkv = (u16*)  alloc((size_t)L_ * 3 * H_ * H_ * 2);
  u16*   wt_o   = (u16*)  alloc((size_t)L_ * H_ * H_ * 2);
  u16*   wt_gu  = (u16*)  alloc((size_t)L_ * 2 * F_ * H_ * 2);
  u16*   wt_d   = (u16*)  alloc((size_t)L_ * H_ * F_ * 2);
  float* h      = (float*)alloc((size_t)M_ * H_ * 4);
  u16*   hn     = (u16*)  alloc((size_t)M_ * H_ * 2);
  u16*   pb16   = (u16*)  alloc((size_t)4 * M_ * H_ * 2);   // bf16 split-K partials
  u16*   qr     = (u16*)  alloc((size_t)M_ * H_ * 2);
  u16*   krr    = (u16*)  alloc((size_t)M_ * H_ * 2);
  u16*   vtb    = (u16*)  alloc((size_t)M_ * H_ * 2);
  u16*   attb   = (u16*)  alloc((size_t)M_ * H_ * 2);
  u16*   actb   = (u16*)  alloc((size_t)M_ * F_ * 2);

  // single prep dispatch: all weight folds + embed
  prep_kernel<<<27136, 256, 0, stream>>>(
      Wqkv, Aqkv, Bqkv, wt_qkv, Wo, Ao, Bo, wt_o,
      Wgu, Agu, Bgu, wt_gu, Wd, Ad, Bd, wt_d, x, sW, sb, h);

  for (int l = 0; l < L_; l++){
    // h += d-partials of previous layer (l>0, 4 bf16 partials), then rms -> hn
    rms_kernel<<<M_, 256, 0, stream>>>(h, pb16, ln1 + (long)l * H_, hn, l > 0 ? 4 : 0);
    // qkv GEMM with fused rope + v-transpose epilogue
    gemm_qkv<<<dim3(16, 24), 256, 0, stream>>>(hn, wt_qkv + (long)l * 3 * H_ * H_,
        qr, krr, vtb);
    attn_kernel<<<dim3(16, B_ * NH_), 256, 0, stream>>>(qr, krr, vtb, attb);
    // o-proj: split-K=4 bf16 partials into pb16[0..3] (Ksteps=16 over Z=4)
    gemm_bt<1><<<dim3(16, 8, 4), 256, 0, stream>>>(attb, wt_o + (long)l * H_ * H_,
        pb16, H_, H_, 16, (long)M_ * H_);
    // h += o-partials (4), rms -> hn
    rms_kernel<<<M_, 256, 0, stream>>>(h, pb16, ln2 + (long)l * H_, hn, 4);
    // fused gate/up GEMM + silu -> actb (bf16), 128x64 tiles
    gemm_gu<<<dim3(16, 44), 256, 0, stream>>>(hn,
        wt_gu + (long)l * 2 * F_ * H_, wt_gu + (long)l * 2 * F_ * H_ + (long)F_ * H_, actb);
    // down-proj: split-K=4 bf16 partials into pb16[0..3] (Ksteps=44 over Z=4)
    gemm_bt<1><<<dim3(16, 8, 4), 256, 0, stream>>>(actb, wt_d + (long)l * H_ * F_,
        pb16, H_, F_, 44, (long)M_ * H_);
  }

  head_kernel<<<M_, 256, 0, stream>>>(h, pb16, lnf, hW, hb, temp, out);
}